// Round 1
// baseline (26.068 us; speedup 1.0000x reference)
//
#include <hip/hip_runtime.h>

// Embedding gather: out[tok, :] = weights[x[tok], :]
// x: [8*8192] int32 in [0,256); weights: [256,512] f32; out: [8*8192, 512] f32.
// Row = 512 f32 = 128 float4. Memory-bound: 128 MiB output write dominates.
__global__ void emb_gather_kernel(const int* __restrict__ x,
                                  const float4* __restrict__ w,
                                  float4* __restrict__ out,
                                  int total_vec4 /* n_tokens * 128 */) {
    const int stride = gridDim.x * blockDim.x;
    for (int i = blockIdx.x * blockDim.x + threadIdx.x; i < total_vec4; i += stride) {
        const int tok = i >> 7;        // 128 float4 per token row
        const int col = i & 127;
        const int idx = x[tok];        // wave-uniform within 64-lane span (L1 hit)
        out[i] = w[(idx << 7) + col];  // weights row in float4 units (512/4 = 128)
    }
}

extern "C" void kernel_launch(void* const* d_in, const int* in_sizes, int n_in,
                              void* d_out, int out_size, void* d_ws, size_t ws_size,
                              hipStream_t stream) {
    const int*    x = (const int*)d_in[0];      // [8, 8192] int32
    const float4* w = (const float4*)d_in[1];   // [256, 512] f32 viewed as [256,128] float4
    float4*     out = (float4*)d_out;           // [65536, 512] f32 viewed as float4

    const int n_tokens   = in_sizes[0];         // 65536
    const int total_vec4 = n_tokens * 128;      // 8,388,608 float4 stores

    const int block = 256;
    const int grid  = 2048;                     // grid-stride covers the rest
    emb_gather_kernel<<<grid, block, 0, stream>>>(x, w, out, total_vec4);
}